// Round 7
// baseline (208.613 us; speedup 1.0000x reference)
//
#include <hip/hip_runtime.h>

#define N_ROWS 32768
#define D_IN 320
#define CB 16
#define N_BOOKS 8192

typedef __attribute__((ext_vector_type(8))) short bf16x8;
typedef __attribute__((ext_vector_type(4))) float f32x4;
#define MFMA __builtin_amdgcn_mfma_f32_16x16x32_bf16
#define AS1 __attribute__((address_space(1)))
#define AS3 __attribute__((address_space(3)))

__device__ __forceinline__ unsigned short bf16rn(float f) {
  unsigned u = __float_as_uint(f);
  u += 0x7fffu + ((u >> 16) & 1u);
  return (unsigned short)(u >> 16);
}
__device__ __forceinline__ float bf16tof(unsigned short h) {
  return __uint_as_float(((unsigned)h) << 16);
}
__device__ __forceinline__ void gload_lds16(const short* g, short* l) {
  __builtin_amdgcn_global_load_lds((const AS1 unsigned int*)g, (AS3 unsigned int*)l, 16, 0, 0);
}

// ================= Kernel A: fused prep (codebook frag-pack) + proj =================
// blocks 0..31: prep. Compact B-frag image, 768 shorts per 16-book tile:
//   lo1 @n*8, hi1 @128+n*8 | lo2 @256.., hi2 @384.. | lo3 @512.., hi3 @640..
// (upper 32 lanes of each MFMA B-frag duplicate the lower 32 -> stored once,
//  read with (lane&31) -> LDS same-address broadcast; B3 upper half aliases B1.)
// blocks 32..543: proj = X @ W^T via bf16 3-split MFMA, fp64 flush; writes
//   tsplit[row][48] = t1[16]|t2[16]|t3[16].
__global__ __launch_bounds__(256, 2) void prep_proj_kernel(const float* __restrict__ cbk,
                                                           const float* __restrict__ x,
                                                           const float* __restrict__ w,
                                                           short* __restrict__ bfrag,
                                                           float* __restrict__ nh_g,
                                                           short* __restrict__ tsplit) {
  __shared__ __align__(16) short wfrag[3][10][64][8];  // 30720 B
  __shared__ __align__(16) float xs[2][64 * 36];       // 18432 B
  const int tid = threadIdx.x;

  if (blockIdx.x < 32) {  // ---------- prep path ----------
    const int j = blockIdx.x * 256 + tid;
    const float4* src = (const float4*)(cbk + (size_t)j * CB);
    float4 a = src[0], b = src[1], c = src[2], d = src[3];
    float ce[16] = {a.x, a.y, a.z, a.w, b.x, b.y, b.z, b.w,
                    c.x, c.y, c.z, c.w, d.x, d.y, d.z, d.w};
    short c1[16], c2[16], c3[16];
    double s = 0.0;
#pragma unroll
    for (int i = 0; i < 16; i++) {
      s += (double)ce[i] * (double)ce[i];
      unsigned short x1 = bf16rn(ce[i]);
      float r1 = ce[i] - bf16tof(x1);
      unsigned short x2 = bf16rn(r1);
      float r2 = r1 - bf16tof(x2);
      unsigned short x3 = bf16rn(r2);
      c1[i] = (short)x1; c2[i] = (short)x2; c3[i] = (short)x3;
    }
    nh_g[j] = (float)(-0.5 * s);
    bf16x8 lo1, hi1, lo2, hi2, lo3, hi3;
#pragma unroll
    for (int i = 0; i < 8; i++) {
      lo1[i] = c1[i]; hi1[i] = c1[i + 8];
      lo2[i] = c2[i]; hi2[i] = c2[i + 8];
      lo3[i] = c3[i]; hi3[i] = c3[i + 8];
    }
    short* base = bfrag + (size_t)(j >> 4) * 768;
    const int n = j & 15;
    *(bf16x8*)(base + 0 + n * 8) = lo1;
    *(bf16x8*)(base + 128 + n * 8) = hi1;
    *(bf16x8*)(base + 256 + n * 8) = lo2;
    *(bf16x8*)(base + 384 + n * 8) = hi2;
    *(bf16x8*)(base + 512 + n * 8) = lo3;
    *(bf16x8*)(base + 640 + n * 8) = hi3;
    return;
  }

  // ---------- proj path ----------
  const int bid = blockIdx.x - 32;
  const int lane = tid & 63;
  const int wv = tid >> 6;

  // stage W: coalesced global reads, split, LDS scatter
  for (int o = 0; o < CB; o++) {
    for (int dbase = 0; dbase < D_IN; dbase += 256) {
      int d = dbase + tid;
      if (d < D_IN) {
        float f = w[o * D_IN + d];
        unsigned short h1 = bf16rn(f);
        float r1 = f - bf16tof(h1);
        unsigned short h2 = bf16rn(r1);
        float r2 = r1 - bf16tof(h2);
        unsigned short h3 = bf16rn(r2);
        int c = d >> 5, qq = (d >> 3) & 3, pos = d & 7;
        int ln = qq * 16 + o;
        wfrag[0][c][ln][pos] = (short)h1;
        wfrag[1][c][ln][pos] = (short)h2;
        wfrag[2][c][ln][pos] = (short)h3;
      }
    }
  }

  const float* xblk = x + (size_t)bid * 64 * D_IN;
  {
    int row = tid >> 2, k0 = (tid & 3) * 8;
    float4 v0 = *(const float4*)(xblk + row * D_IN + k0);
    float4 v1 = *(const float4*)(xblk + row * D_IN + k0 + 4);
    *(float4*)&xs[0][row * 36 + k0] = v0;
    *(float4*)&xs[0][row * 36 + k0 + 4] = v1;
  }
  __syncthreads();

  const int m = lane & 15, q = lane >> 4;
  double dacc[4] = {0.0, 0.0, 0.0, 0.0};
  for (int c = 0; c < 10; c++) {
    const int buf = c & 1;
    if (c < 9) {
      int row = tid >> 2, k0 = (tid & 3) * 8;
      float4 v0 = *(const float4*)(xblk + row * D_IN + (c + 1) * 32 + k0);
      float4 v1 = *(const float4*)(xblk + row * D_IN + (c + 1) * 32 + k0 + 4);
      *(float4*)&xs[buf ^ 1][row * 36 + k0] = v0;
      *(float4*)&xs[buf ^ 1][row * 36 + k0 + 4] = v1;
    }
    const float* xp = &xs[buf][(wv * 16 + m) * 36 + q * 8];
    float4 xa = *(const float4*)xp;
    float4 xb = *(const float4*)(xp + 4);
    float xe[8] = {xa.x, xa.y, xa.z, xa.w, xb.x, xb.y, xb.z, xb.w};
    bf16x8 a1, a2, a3;
#pragma unroll
    for (int j = 0; j < 8; j++) {
      unsigned short h1 = bf16rn(xe[j]);
      float r1 = xe[j] - bf16tof(h1);
      unsigned short h2 = bf16rn(r1);
      float r2 = r1 - bf16tof(h2);
      unsigned short h3 = bf16rn(r2);
      a1[j] = (short)h1; a2[j] = (short)h2; a3[j] = (short)h3;
    }
    bf16x8 b1 = *(const bf16x8*)wfrag[0][c][lane];
    bf16x8 b2 = *(const bf16x8*)wfrag[1][c][lane];
    bf16x8 b3 = *(const bf16x8*)wfrag[2][c][lane];
    f32x4 g = {0.f, 0.f, 0.f, 0.f};
    g = MFMA(a1, b1, g, 0, 0, 0);
#pragma unroll
    for (int r = 0; r < 4; r++) dacc[r] += (double)g[r];
    g = (f32x4){0.f, 0.f, 0.f, 0.f};
    g = MFMA(a2, b1, g, 0, 0, 0);
    g = MFMA(a1, b2, g, 0, 0, 0);
#pragma unroll
    for (int r = 0; r < 4; r++) dacc[r] += (double)g[r];
    g = (f32x4){0.f, 0.f, 0.f, 0.f};
    g = MFMA(a3, b1, g, 0, 0, 0);
    g = MFMA(a1, b3, g, 0, 0, 0);
    g = MFMA(a2, b2, g, 0, 0, 0);
#pragma unroll
    for (int r = 0; r < 4; r++) dacc[r] += (double)g[r];
    __syncthreads();
  }

  float* tl = (float*)xs;  // 64 rows x stride 17
#pragma unroll
  for (int r = 0; r < 4; r++) tl[(wv * 16 + q * 4 + r) * 17 + m] = (float)dacc[r];
  __syncthreads();
  {
    int row_l = tid >> 2, p = tid & 3;
    short h1[4], h2[4], h3[4];
#pragma unroll
    for (int i = 0; i < 4; i++) {
      float f = tl[row_l * 17 + p * 4 + i];
      unsigned short a = bf16rn(f);
      float r1 = f - bf16tof(a);
      unsigned short b = bf16rn(r1);
      float r2 = r1 - bf16tof(b);
      unsigned short cc = bf16rn(r2);
      h1[i] = (short)a; h2[i] = (short)b; h3[i] = (short)cc;
    }
    size_t base = (size_t)(bid * 64 + row_l) * 48;
    *(short4*)(tsplit + base + p * 4) = make_short4(h1[0], h1[1], h1[2], h1[3]);
    *(short4*)(tsplit + base + 16 + p * 4) = make_short4(h2[0], h2[1], h2[2], h2[3]);
    *(short4*)(tsplit + base + 32 + p * 4) = make_short4(h3[0], h3[1], h3[2], h3[3]);
  }
}

// ================= Kernel B: scores + fused top-2 argmax =================
// grid = 128 row-groups x 8 book-eighths = 1024 blocks, 4 blocks/CU.
// Block: 256 rows (4 waves x 4 row-tiles); 1024 books = 8 substages x 8 bt,
// substage 12 KB double-buffered via global_load_lds. argmax m = t.c - 0.5||c||^2.
#define SC_H 8

__global__ __launch_bounds__(256, 4) void score_kernel(const short* __restrict__ tsplit,
                                                       const short* __restrict__ bfrag,
                                                       const float* __restrict__ nh_g,
                                                       float* __restrict__ cs1,
                                                       float* __restrict__ cs2,
                                                       int* __restrict__ cidx) {
  __shared__ __align__(16) short ldsb[2][6144];  // 2 x 12 KB (8 bt x 768 shorts)
  __shared__ float ldsnh[1024];                  // 4 KB
  const int tid = threadIdx.x;
  const int lane = tid & 63;
  const int wv = tid >> 6;
  const int m = lane & 15, q = lane >> 4;
  const int rb = blockIdx.x & 127;
  const int h = blockIdx.x >> 7;
  const int rowbase = rb * 256;

  bf16x8 A12[4], A13[4];
#pragma unroll
  for (int rt = 0; rt < 4; rt++) {
    int row = rowbase + wv * 64 + rt * 16 + m;
    const short* tp = tsplit + (size_t)row * 48;
    A12[rt] = *(const bf16x8*)(tp + q * 8);
    A13[rt] = *(const bf16x8*)(tp + q * 8 + ((q >= 2) ? 16 : 0));
  }
  for (int i = tid; i < 1024; i += 256) ldsnh[i] = nh_g[h * 1024 + i];

  const short* gq = bfrag + (size_t)h * 49152;  // 64 bt x 768 shorts per eighth
  {
    const short* g0 = gq + wv * 1536 + lane * 8;
#pragma unroll
    for (int it = 0; it < 3; it++)
      gload_lds16(g0 + it * 512, &ldsb[0][wv * 1536 + it * 512]);
  }

  float s1[4][4], s2[4][4];
  int i1[4][4];
#pragma unroll
  for (int rt = 0; rt < 4; rt++)
#pragma unroll
    for (int r = 0; r < 4; r++) { s1[rt][r] = -3.4e38f; s2[rt][r] = -3.4e38f; i1[rt][r] = 0; }

  __syncthreads();  // drains substage-0 loads + nh writes

  for (int sc = 0; sc < 8; sc++) {
    const int cur = sc & 1;
    if (sc < 7) {
      const short* gs = gq + (sc + 1) * 6144 + wv * 1536 + lane * 8;
#pragma unroll
      for (int it = 0; it < 3; it++)
        gload_lds16(gs + it * 512, &ldsb[cur ^ 1][wv * 1536 + it * 512]);
    }
#pragma unroll 2
    for (int bt = 0; bt < 8; bt++) {
      const short* bp = &ldsb[cur][bt * 768];
      const int l31 = (lane & 31) * 8;
      bf16x8 b1 = *(const bf16x8*)(bp + l31);          // lanes 32-63 broadcast lower
      bf16x8 b2 = *(const bf16x8*)(bp + 256 + l31);
      bf16x8 b3 = *(const bf16x8*)(bp + ((lane < 32) ? 512 : 0) + l31);  // upper = B1 data
      const int btg = sc * 8 + bt;
      float nh0 = ldsnh[btg * 16 + m];
      f32x4 ci = {nh0, nh0, nh0, nh0};
      const int colv = h * 1024 + btg * 16 + m;
#pragma unroll
      for (int rt = 0; rt < 4; rt++) {
        f32x4 acc = MFMA(A12[rt], b1, ci, 0, 0, 0);
        acc = MFMA(A12[rt], b2, acc, 0, 0, 0);
        acc = MFMA(A13[rt], b3, acc, 0, 0, 0);
#pragma unroll
        for (int r = 0; r < 4; r++) {
          float v = acc[r];
          float s1o = s1[rt][r];
          s2[rt][r] = __builtin_amdgcn_fmed3f(v, s1o, s2[rt][r]);
          s1[rt][r] = fmaxf(s1o, v);
          i1[rt][r] = (v > s1o) ? colv : i1[rt][r];  // strict: earlier bt wins ties
        }
      }
    }
    __syncthreads();
  }

  // cross-lane top-2 merge over 16 column-lanes (ties -> min index)
#pragma unroll
  for (int rt = 0; rt < 4; rt++)
#pragma unroll
    for (int r = 0; r < 4; r++) {
      float a1v = s1[rt][r], a2v = s2[rt][r];
      int ai = i1[rt][r];
#pragma unroll
      for (int msk = 1; msk <= 8; msk <<= 1) {
        float o1 = __shfl_xor(a1v, msk);
        float o2 = __shfl_xor(a2v, msk);
        int oi = __shfl_xor(ai, msk);
        if (o1 > a1v) {
          a2v = fmaxf(a1v, o2); a1v = o1; ai = oi;
        } else {
          a2v = fmaxf(a2v, o1);
          if (o1 == a1v && oi < ai) ai = oi;
        }
      }
      if (m == 0) {
        int row = rowbase + wv * 64 + rt * 16 + q * 4 + r;
        size_t idx = (size_t)h * N_ROWS + row;
        cs1[idx] = a1v; cs2[idx] = a2v; cidx[idx] = ai;
      }
    }
}

// ================= Kernel C: merge eighths + exact fp64 rescore of near-ties ==========
#define MARGIN_EPS 1.0e-4f

__global__ __launch_bounds__(256) void reduce_fb_kernel(const float* __restrict__ cs1,
                                                        const float* __restrict__ cs2,
                                                        const int* __restrict__ cidx,
                                                        const float* __restrict__ x,
                                                        const float* __restrict__ w,
                                                        const float* __restrict__ codebook,
                                                        int* __restrict__ out) {
  __shared__ int flagged[256];
  __shared__ double ps[16][17];
  __shared__ double tsh[16];
  __shared__ double rs[256];
  __shared__ int ri[256];
  const int tid = threadIdx.x;
  const int base = blockIdx.x * 256;
  {
    const int r = base + tid;
    float S1 = -3.4e38f, S2 = -3.4e38f;
    int I = 0;
#pragma unroll
    for (int h = 0; h < SC_H; h++) {  // ascending + strict '>' => min index on ties
      size_t idx = (size_t)h * N_ROWS + r;
      float v1 = cs1[idx], v2 = cs2[idx];
      if (v1 > S1) {
        S2 = fmaxf(S1, v2); S1 = v1; I = cidx[idx];
      } else {
        S2 = fmaxf(S2, v1);
      }
    }
    out[r] = I;
    flagged[tid] = (S1 - S2 < MARGIN_EPS) ? 1 : 0;
  }
  __syncthreads();

  for (int rr = 0; rr < 256; rr++) {
    if (!flagged[rr]) continue;  // block-uniform
    const int row = base + rr;
    {
      int o = tid & 15, c = tid >> 4;
      double p = 0.0;
      for (int k = 0; k < 20; k++) {
        int d = c * 20 + k;
        p = fma((double)x[(size_t)row * D_IN + d], (double)w[o * D_IN + d], p);
      }
      ps[c][o] = p;
    }
    __syncthreads();
    if (tid < 16) {
      double t = 0.0;
      for (int c = 0; c < 16; c++) t += ps[c][tid];
      tsh[tid] = t;
    }
    __syncthreads();
    double t[16];
#pragma unroll
    for (int i = 0; i < 16; i++) t[i] = tsh[i];
    double bs = -1.0e300;
    int bi = 0;
    for (int j = tid; j < N_BOOKS; j += 256) {
      const float* cp = codebook + (size_t)j * CB;
      double dot = 0.0, cc = 0.0;
#pragma unroll
      for (int i = 0; i < 16; i++) {
        double cv = (double)cp[i];
        dot = fma(t[i], cv, dot);
        cc = fma(cv, cv, cc);
      }
      double mv = dot - 0.5 * cc;
      if (mv > bs) { bs = mv; bi = j; }  // ascending j: first wins
    }
    rs[tid] = bs; ri[tid] = bi;
    __syncthreads();
    for (int s = 128; s > 0; s >>= 1) {
      if (tid < s) {
        double os = rs[tid + s]; int oi = ri[tid + s];
        if (os > rs[tid] || (os == rs[tid] && oi < ri[tid])) { rs[tid] = os; ri[tid] = oi; }
      }
      __syncthreads();
    }
    if (tid == 0) out[row] = ri[0];
    __syncthreads();
  }
}

extern "C" void kernel_launch(void* const* d_in, const int* in_sizes, int n_in,
                              void* d_out, int out_size, void* d_ws, size_t ws_size,
                              hipStream_t stream) {
  (void)in_sizes; (void)n_in; (void)out_size; (void)ws_size;
  const float* x = (const float*)d_in[0];
  // d_in[1] = mask_time_indices: all-ones -> flatten; unused
  const float* w = (const float*)d_in[2];
  const float* codebook = (const float*)d_in[3];

  char* ws = (char*)d_ws;
  short* tsplit = (short*)(ws);             // 3 MB   @0
  short* bfrag = (short*)(ws + 3145728);    // 768 KB @3M
  float* nh_g = (float*)(ws + 3932160);     // 32 KB
  float* cs1 = (float*)(ws + (4 << 20));    // 1 MB
  float* cs2 = (float*)(ws + (5 << 20));    // 1 MB
  int* cidx = (int*)(ws + (6 << 20));       // 1 MB (ends at 7 MB)
  int* out = (int*)d_out;

  prep_proj_kernel<<<32 + N_ROWS / 64, 256, 0, stream>>>(codebook, x, w, bfrag, nh_g, tsplit);
  score_kernel<<<128 * SC_H, 256, 0, stream>>>(tsplit, bfrag, nh_g, cs1, cs2, cidx);
  reduce_fb_kernel<<<N_ROWS / 256, 256, 0, stream>>>(cs1, cs2, cidx, x, w, codebook, out);
}